// Round 9
// baseline (549.865 us; speedup 1.0000x reference)
//
#include <hip/hip_runtime.h>

#define HID 2048
#define INTER 5632
#define KVW 256
#define NL 6
#define RMS_EPS 1e-6f

#define NB 512     // 2 blocks per CU -> 32 waves/CU (the round-9 variable)
#define NT 1024    // 16 waves

typedef unsigned int uint;

// ---- barrier lines: 1KB apart; monotonic counters, split arrive/wait ----
#define LSTRIDE 256            // uints between lines
#define LG0 0                  // 16 lines: partials ready  (512 arrivals/layer)
#define LG2 16                 // 16 lines: h' ready        (512/layer)
#define LG3 32                 // 16 lines: inter ready     (512/layer)
#define LG4 48                 // 16 lines: h'' ready       (512/layer)
#define LN1 64                 // 8 lines:  ctx ready       (32/layer)
#define LNM 72                 // 8 lines:  partial2 ready  (32/layer)
#define BAR_UINTS (80 * 256)   // 20480

// ---- ws float offsets ----
#define F_H     20480
#define F_CTX   22528
#define F_PART  24576          // 512*256
#define F_PART2 155648         // 32*256
#define F_INTER 163840         // 5632
#define F_GSC   169472

// ---------------- LLC (relaxed agent-scope) access ----------------
__device__ __forceinline__ float ld_llc(const float* p) {
    return __hip_atomic_load(p, __ATOMIC_RELAXED, __HIP_MEMORY_SCOPE_AGENT);
}
__device__ __forceinline__ void st_llc(float* p, float v) {
    __hip_atomic_store(p, v, __ATOMIC_RELAXED, __HIP_MEMORY_SCOPE_AGENT);
}

// ---------------- wave helpers ----------------
__device__ __forceinline__ float waveAllSum(float v) {
#pragma unroll
    for (int m = 32; m > 0; m >>= 1) v += __shfl_xor(v, m, 64);
    return v;
}
__device__ __forceinline__ float waveAllMax(float v) {
#pragma unroll
    for (int m = 32; m > 0; m >>= 1) v = fmaxf(v, __shfl_xor(v, m, 64));
    return v;
}
__device__ __forceinline__ float dot4(float4 a, float4 b, float acc) {
    acc = fmaf(a.x, b.x, acc);
    acc = fmaf(a.y, b.y, acc);
    acc = fmaf(a.z, b.z, acc);
    acc = fmaf(a.w, b.w, acc);
    return acc;
}

// ---------------- split monotonic barriers ----------------
// __syncthreads in arrive drains vmcnt -> this block's sc1 stores are at the
// LLC before the arrival add; waiters poll arrival lines with gentle sleep.
__device__ __forceinline__ void arrive16(uint* bar, int grpLine, int bid) {
    __syncthreads();
    if (threadIdx.x == 0)
        __hip_atomic_fetch_add(bar + (grpLine + (bid & 15)) * LSTRIDE, 1u,
                               __ATOMIC_RELAXED, __HIP_MEMORY_SCOPE_AGENT);
}
template <int SLP>
__device__ __forceinline__ void wait16(const uint* bar, int grpLine, uint target) {
    if (threadIdx.x < 16) {
        const uint* p = bar + (grpLine + threadIdx.x) * LSTRIDE;
        while (true) {
            uint v = __hip_atomic_load(p, __ATOMIC_RELAXED, __HIP_MEMORY_SCOPE_AGENT);
#pragma unroll
            for (int m = 8; m > 0; m >>= 1) v += __shfl_xor(v, m, 64);
            if (v >= target) break;
            __builtin_amdgcn_s_sleep(SLP);
        }
    }
    __syncthreads();
}
__device__ __forceinline__ void arrive8(uint* bar, int grpLine, int bid) {
    __syncthreads();
    if (threadIdx.x == 0)
        __hip_atomic_fetch_add(bar + (grpLine + (bid & 7)) * LSTRIDE, 1u,
                               __ATOMIC_RELAXED, __HIP_MEMORY_SCOPE_AGENT);
}
template <int SLP>
__device__ __forceinline__ void wait8(const uint* bar, int grpLine, uint target) {
    if (threadIdx.x < 8) {
        const uint* p = bar + (grpLine + threadIdx.x) * LSTRIDE;
        while (true) {
            uint v = __hip_atomic_load(p, __ATOMIC_RELAXED, __HIP_MEMORY_SCOPE_AGENT);
#pragma unroll
            for (int m = 4; m > 0; m >>= 1) v += __shfl_xor(v, m, 64);
            if (v >= target) break;
            __builtin_amdgcn_s_sleep(SLP);
        }
    }
    __syncthreads();
}

// rmsnorm(h, nw) -> xbuf[2048] (unit-stride loads); aux[0..16) scratch
__device__ __forceinline__ void block_rms_norm(const float* __restrict__ h,
                                               const float* __restrict__ nw,
                                               float* xbuf, float* aux) {
    const int tid = threadIdx.x, lane = tid & 63, wid = tid >> 6;
    const float a = ld_llc(h + tid), b = ld_llc(h + 1024 + tid);
    float ss = a * a + b * b;
    ss = waveAllSum(ss);
    if (lane == 0) aux[wid] = ss;
    __syncthreads();
    float tot = 0.f;
#pragma unroll
    for (int i = 0; i < 16; ++i) tot += aux[i];
    const float f = rsqrtf(tot * (1.0f / (float)HID) + RMS_EPS);
    xbuf[tid]        = a * f * nw[tid];
    xbuf[1024 + tid] = b * f * nw[1024 + tid];
    __syncthreads();
}

// ---------------- init ----------------
__global__ __launch_bounds__(1024) void k_init(const float* __restrict__ x,
                                               float* __restrict__ ws) {
    uint* bar = (uint*)ws;
#pragma unroll
    for (int k = 0; k < 20; ++k) bar[k * 1024 + threadIdx.x] = 0u;
    float* h = ws + F_H;
    h[threadIdx.x] = x[threadIdx.x];
    h[1024 + threadIdx.x] = x[1024 + threadIdx.x];
}

// ---------------- persistent backbone: 512 blocks, 2/CU, 32 waves/CU ----------------
__global__ __launch_bounds__(NT, 8) void k_backbone(
    const float* __restrict__ kvw,
    const float* __restrict__ n1w, const float* __restrict__ n2w,
    const float* __restrict__ q_w, const float* __restrict__ o_w,
    const float* __restrict__ shg_w,
    const float* __restrict__ g_w, const float* __restrict__ u_w,
    const float* __restrict__ dn_w,
    float* __restrict__ out, float* __restrict__ ws) {
    __shared__ float stage[12288];   // 48KB: [0..8192) Wq / WgWu-tasks0-3; [8192..12288) Wd
    __shared__ float buf[5632];      // 22KB
    __shared__ float aux[64];

    uint*  bar      = (uint*)ws;
    float* h        = ws + F_H;
    float* ctx      = ws + F_CTX;
    float* partial  = ws + F_PART;
    float* partial2 = ws + F_PART2;
    float* inter    = ws + F_INTER;
    float* gsc      = ws + F_GSC;

    const int bid  = blockIdx.x;
    const int tid  = threadIdx.x;
    const int lane = tid & 63, wid = tid >> 6;
    const int r    = wid >> 2;          // this wave's row (0..3) within block's 4 rows
    const int q    = wid & 3;           // quarter
    const int j256 = tid & 255, grp = tid >> 8;

    // stage layer-0 Wq slice: 4 rows x 8 chunks = 32 chunks of 256 floats
    {
#pragma unroll
        for (int m_ = 0; m_ < 2; ++m_) {
            const int m = wid + m_ * 16;            // 0..31
            const int rr = m >> 3, c = m & 7;
            ((float4*)(stage + m * 256))[lane] =
                ((const float4*)(q_w + (size_t)(bid * 4 + rr) * HID + c * 256))[lane];
        }
    }

    for (int L = 0; L < NL; ++L) {
        const float* Wo = o_w  + (size_t)L * HID * HID;
        const float* Wg = g_w  + (size_t)L * INTER * HID;
        const float* Wu = u_w  + (size_t)L * INTER * HID;
        const float* Wd = dn_w + (size_t)L * HID * INTER;
        const uint tgt512 = 512u * (L + 1), tgt32 = 32u * (L + 1);

        // ---- P1: q rows (Wq in LDS) + fused partial scores for own 4 rows ----
        block_rms_norm(h, n1w + L * HID, buf, aux);
        {
            const float4* X4 = (const float4*)buf;
            const float4* S4 = (const float4*)stage;
            float acc = 0.f;
#pragma unroll
            for (int k = 0; k < 2; ++k) {
                const int c = q * 2 + k;
                acc = dot4(S4[(r * 8 + c) * 64 + lane], X4[c * 64 + lane], acc);
            }
            acc = waveAllSum(acc);
            if (lane == 0) aux[16 + wid] = acc;
            __syncthreads();
        }
        {   // partial[bid][j] = sum over this block's 4 q rows
            const float qg = aux[16 + 4 * grp] + aux[16 + 4 * grp + 1] +
                             aux[16 + 4 * grp + 2] + aux[16 + 4 * grp + 3];
            float* ps = buf;
            ps[grp * 256 + j256] = qg * kvw[(size_t)(bid * 4 + grp) * KVW + j256];
            __syncthreads();
            if (tid < 256)
                st_llc(partial + (size_t)bid * 256 + tid,
                       ps[tid] + ps[256 + tid] + ps[512 + tid] + ps[768 + tid]);
        }
        arrive16(bar, LG0, bid);

        // ---- P2: 32 attention blocks reduce 512 partials -> softmax -> ctx ----
        if (bid < 32) {
            wait16<8>(bar, LG0, tgt512);
            {   // stage1: sum my 16 partial vectors -> partial2[bid]
                float s = 0.f;
#pragma unroll
                for (int b = 0; b < 4; ++b)
                    s += ld_llc(partial + (size_t)(bid * 16 + grp * 4 + b) * 256 + j256);
                float* ps = buf;
                ps[grp * 256 + j256] = s;
                __syncthreads();
                if (tid < 256)
                    st_llc(partial2 + (size_t)bid * 256 + tid,
                           ps[tid] + ps[256 + tid] + ps[512 + tid] + ps[768 + tid]);
            }
            arrive8(bar, LNM, bid);
            wait8<4>(bar, LNM, tgt32);
            {   // stage2: total scores -> softmax -> ctx strip (64 rows)
                float s = 0.f;
#pragma unroll
                for (int c = 0; c < 8; ++c)
                    s += ld_llc(partial2 + (size_t)(grp * 8 + c) * 256 + j256);
                float* sp = buf;
                sp[grp * 256 + j256] = s;
                __syncthreads();
                float sv = -3.4e38f;
                if (tid < 256) sv = sp[tid] + sp[256 + tid] + sp[512 + tid] + sp[768 + tid];
                float mx = waveAllMax(sv);
                if (lane == 0 && wid < 4) aux[wid] = mx;
                __syncthreads();
                mx = fmaxf(fmaxf(aux[0], aux[1]), fmaxf(aux[2], aux[3]));
                const float e = (tid < 256) ? __expf(sv - mx) : 0.f;
                float ts = waveAllSum(e);
                if (lane == 0 && wid < 4) aux[8 + wid] = ts;
                __syncthreads();
                const float den = aux[8] + aux[9] + aux[10] + aux[11];
                float* pj = buf + 1024;
                if (tid < 256) pj[tid] = e / den;
                __syncthreads();
                const float4* p4  = (const float4*)pj;
                const float4* kv4 = (const float4*)kvw;
#pragma unroll
                for (int r2 = 0; r2 < 4; ++r2) {
                    const int i = bid * 64 + wid * 4 + r2;
                    float a = dot4(kv4[(size_t)i * 64 + lane], p4[lane], 0.f);
                    a = waveAllSum(a);
                    if (lane == 0) st_llc(ctx + i, a);
                }
            }
            arrive8(bar, LN1, bid);
        }
        // ---- all blocks: stage WgWu tasks 0..3 (32KB) during the bubble ----
        {
#pragma unroll
            for (int m_ = 0; m_ < 2; ++m_) {
                const int m = wid + m_ * 16;        // 0..31
                const int t = m >> 3, c = m & 7;
                const int jj = bid * 11 + (t >> 1);
                const float* src = (((t & 1) ? Wu : Wg) + (size_t)jj * HID) + c * 256;
                ((float4*)(stage + m * 256))[lane] = ((const float4*)src)[lane];
            }
        }
        wait8<16>(bar, LN1, tgt32);

        // ---- P3: h[row] += Wo[row,:] @ ctx (live, 2 chunks per wave) ----
        {
            buf[tid]        = ld_llc(ctx + tid);
            buf[1024 + tid] = ld_llc(ctx + 1024 + tid);
            __syncthreads();
            const float4* X4 = (const float4*)buf;
            const float4* Wr = (const float4*)(Wo + (size_t)(bid * 4 + r) * HID);
            float acc = 0.f;
#pragma unroll
            for (int k = 0; k < 2; ++k) {
                const int c = q * 2 + k;
                acc = dot4(Wr[c * 64 + lane], X4[c * 64 + lane], acc);
            }
            acc = waveAllSum(acc);
            if (lane == 0) aux[16 + wid] = acc;
            __syncthreads();
            if (tid < 4) {
                const int rr = bid * 4 + tid;
                st_llc(h + rr, ld_llc(h + rr) + aux[16 + 4 * tid] + aux[16 + 4 * tid + 1] +
                                aux[16 + 4 * tid + 2] + aux[16 + 4 * tid + 3]);
            }
        }
        arrive16(bar, LG2, bid);
        wait16<16>(bar, LG2, tgt512);

        // ---- P4: inter = silu(Wg@x2)*(Wu@x2); tasks 0-3 from LDS, rest live ----
        block_rms_norm(h, n2w + L * HID, buf, aux);
        {
            float* res = buf + 2048;   // 22 results
            const float4* X4 = (const float4*)buf;
            const float4* S4 = (const float4*)stage;
            for (int t = wid; t < 22; t += 16) {
                float acc = 0.f;
                if (t < 4) {
#pragma unroll
                    for (int c = 0; c < 8; ++c)
                        acc = dot4(S4[(t * 8 + c) * 64 + lane], X4[c * 64 + lane], acc);
                } else {
                    const int jj = bid * 11 + (t >> 1);
                    const float4* Wr = (const float4*)(((t & 1) ? Wu : Wg) + (size_t)jj * HID);
#pragma unroll
                    for (int c = 0; c < 8; ++c)
                        acc = dot4(Wr[c * 64 + lane], X4[c * 64 + lane], acc);
                }
                acc = waveAllSum(acc);
                if (lane == 0) res[t] = acc;
            }
            if (bid == 0) {
                const float* sw = shg_w + L * HID;
                float pv = sw[tid] * buf[tid] + sw[1024 + tid] * buf[1024 + tid];
                pv = waveAllSum(pv);
                if (lane == 0) aux[32 + wid] = pv;
            }
            __syncthreads();
            if (tid < 11) {
                const float gv = res[2 * tid], uv = res[2 * tid + 1];
                st_llc(inter + bid * 11 + tid, gv / (1.f + __expf(-gv)) * uv);
            }
            if (bid == 0 && tid == 0) {
                float gl = 0.f;
#pragma unroll
                for (int i = 0; i < 16; ++i) gl += aux[32 + i];
                st_llc(gsc, 1.f / (1.f + __expf(-gl)));
            }
        }
        arrive16(bar, LG3, bid);
        // ---- stage Wd: 4 rows x chunks 0..3 (16KB) during the inter-wait ----
        {
            const int m = wid;                      // 0..15
            const int rr = m >> 2, c = m & 3;
            const float* src = Wd + (size_t)(bid * 4 + rr) * INTER + c * 256;
            ((float4*)(stage + 8192 + m * 256))[lane] = ((const float4*)src)[lane];
        }
        wait16<16>(bar, LG3, tgt512);

        // ---- P5: h[row] += g * (Wd[row,:] @ inter); chunks 0-3 from LDS ----
        {
#pragma unroll
            for (int k = 0; k < 6; ++k) {
                const int idx = k * 1024 + tid;
                if (idx < INTER) buf[idx] = ld_llc(inter + idx);
            }
            __syncthreads();
            const float gg = ld_llc(gsc);
            const float4* I4 = (const float4*)buf;
            const float4* S4 = (const float4*)stage;
            const float4* D4 = (const float4*)(Wd + (size_t)(bid * 4 + r) * INTER);
            float acc = 0.f;
            if (q == 0) {
#pragma unroll
                for (int c = 0; c < 4; ++c)
                    acc = dot4(S4[(32 + r * 4 + c) * 64 + lane], I4[c * 64 + lane], acc);
#pragma unroll
                for (int c = 4; c < 6; ++c)
                    acc = dot4(D4[c * 64 + lane], I4[c * 64 + lane], acc);
            } else if (q == 1) {
#pragma unroll
                for (int c = 6; c < 12; ++c)
                    acc = dot4(D4[c * 64 + lane], I4[c * 64 + lane], acc);
            } else if (q == 2) {
#pragma unroll
                for (int c = 12; c < 17; ++c)
                    acc = dot4(D4[c * 64 + lane], I4[c * 64 + lane], acc);
            } else {
#pragma unroll
                for (int c = 17; c < 22; ++c)
                    acc = dot4(D4[c * 64 + lane], I4[c * 64 + lane], acc);
            }
            acc = waveAllSum(acc);
            if (lane == 0) aux[16 + wid] = acc;
            __syncthreads();
            if (tid < 4) {
                const int rr = bid * 4 + tid;
                const float v = ld_llc(h + rr) +
                    gg * (aux[16 + 4 * tid] + aux[16 + 4 * tid + 1] +
                          aux[16 + 4 * tid + 2] + aux[16 + 4 * tid + 3]);
                if (L == NL - 1) out[rr] = v;
                else st_llc(h + rr, v);
            }
        }
        if (L < NL - 1) {
            arrive16(bar, LG4, bid);
            // stage next-layer Wq (32KB) during the h''-wait
            const float* Wqn = q_w + (size_t)(L + 1) * HID * HID;
#pragma unroll
            for (int m_ = 0; m_ < 2; ++m_) {
                const int m = wid + m_ * 16;
                const int rr = m >> 3, c = m & 7;
                ((float4*)(stage + m * 256))[lane] =
                    ((const float4*)(Wqn + (size_t)(bid * 4 + rr) * HID + c * 256))[lane];
            }
            wait16<16>(bar, LG4, tgt512);
        }
    }
}

// ---------------- host ----------------
extern "C" void kernel_launch(void* const* d_in, const int* in_sizes, int n_in,
                              void* d_out, int out_size, void* d_ws, size_t ws_size,
                              hipStream_t stream) {
    const float* x     = (const float*)d_in[0];
    const float* kvw   = (const float*)d_in[1];
    const float* n1w   = (const float*)d_in[2];
    const float* n2w   = (const float*)d_in[3];
    const float* q_w   = (const float*)d_in[4];
    // d_in[5]=k_w, d_in[6]=v_w: dead in reference
    const float* o_w   = (const float*)d_in[7];
    // d_in[8]=router_w: dead
    const float* shg_w = (const float*)d_in[9];
    const float* g_w   = (const float*)d_in[10];
    const float* u_w   = (const float*)d_in[11];
    const float* dn_w  = (const float*)d_in[12];
    float* out = (float*)d_out;
    float* ws  = (float*)d_ws;

    k_init<<<1, 1024, 0, stream>>>(x, ws);
    k_backbone<<<NB, NT, 0, stream>>>(kvw, n1w, n2w, q_w, o_w, shg_w,
                                      g_w, u_w, dn_w, out, ws);
}